// Round 5
// baseline (190.623 us; speedup 1.0000x reference)
//
#include <hip/hip_runtime.h>
#include <math.h>

#define SL   1024
#define BS   64
#define HID  1024
#define D2   2048            // 2*CELL
#define KCAT 3072            // 2*CELL + HID
#define CELL 1024
#define NSC  16              // s-slices for the fused attention kernel
#define SPB  (SL / NSC)      // 64 s per block
#define KS5  16              // K-split for the output GEMM
#define JS5  (KCAT / KS5)    // 192 j per slice

typedef float vfloat4 __attribute__((ext_vector_type(4)));

__device__ __forceinline__ float4 ntload(const float* p) {
    vfloat4 v = __builtin_nontemporal_load(reinterpret_cast<const vfloat4*>(p));
    return make_float4(v.x, v.y, v.z, v.w);
}

__device__ __forceinline__ float waveReduceAdd(float v) {
#pragma unroll
    for (int o = 32; o >= 1; o >>= 1) v += __shfl_xor(v, o, 64);
    return v;
}

// ---------------------------------------------------------------------------
// K_fused: per (b, s-slice) block.
// Pass 1: scores for the 64 s in the slice (block dot over HID; h_t slice
//         kept in registers; one LDS reduce per s, double-buffered red[]).
// Pass 2: slice-partial context with weights exp(score - m_slice) * mask.
// Also writes scoresT[b][s], maskT[b][s] (both coalesced consumers later).
// ---------------------------------------------------------------------------
__global__ __launch_bounds__(256) void k_fused(
    const float* __restrict__ Wh, const float* __restrict__ ht,
    const float* __restrict__ mask, const float* __restrict__ hs,
    float* __restrict__ scoresT, float* __restrict__ maskT,
    float* __restrict__ partial) {
    __shared__ float red[2][4];
    __shared__ float sco[SPB];
    __shared__ float msk[SPB];
    const int b = blockIdx.x, sc = blockIdx.y, s0 = sc * SPB;
    const int t = threadIdx.x, wave = t >> 6, lane = t & 63;

    const float4 h4 = *reinterpret_cast<const float4*>(ht + (size_t)b * HID + t * 4);
    if (t < SPB) {
        float mv = mask[(size_t)(s0 + t) * BS + b];
        msk[t] = mv;
        maskT[(size_t)b * SL + s0 + t] = mv;
    }

    // ---- pass 1: scores ----
    const float* wbase = Wh + ((size_t)s0 * BS + b) * HID + t * 4;
    const size_t wstride = (size_t)BS * HID;
    float m = -INFINITY;
    float4 wnext = ntload(wbase);
    for (int s = 0; s < SPB; ++s) {
        float4 w = wnext;
        if (s + 1 < SPB) wnext = ntload(wbase + (size_t)(s + 1) * wstride);
        float p = fmaf(w.x, h4.x, fmaf(w.y, h4.y, fmaf(w.z, h4.z, w.w * h4.w)));
        p = waveReduceAdd(p);
        if (lane == 0) red[s & 1][wave] = p;
        __syncthreads();
        float score = red[s & 1][0] + red[s & 1][1] + red[s & 1][2] + red[s & 1][3];
        if (t == 0) sco[s] = score;
        m = fmaxf(m, score);          // identical in every thread
    }
    __syncthreads();
    if (t < SPB) {
        float sv = sco[t];
        scoresT[(size_t)b * SL + s0 + t] = sv;
        sco[t] = __expf(sv - m) * msk[t];   // slice-local weights, <= 1
    }
    __syncthreads();

    // ---- pass 2: weighted context over the slice ----
    const float* hbase = hs + ((size_t)s0 * BS + b) * D2 + t * 8;
    const size_t hstride = (size_t)BS * D2;
    float4 a0 = make_float4(0.f, 0.f, 0.f, 0.f);
    float4 a1 = make_float4(0.f, 0.f, 0.f, 0.f);
    for (int s = 0; s < SPB; s += 8) {
        float4 v[8][2];
#pragma unroll
        for (int j = 0; j < 8; ++j) {
            const float* p = hbase + (size_t)(s + j) * hstride;
            v[j][0] = ntload(p);
            v[j][1] = ntload(p + 4);
        }
#pragma unroll
        for (int j = 0; j < 8; ++j) {
            const float wgt = sco[s + j];
            a0.x = fmaf(wgt, v[j][0].x, a0.x); a0.y = fmaf(wgt, v[j][0].y, a0.y);
            a0.z = fmaf(wgt, v[j][0].z, a0.z); a0.w = fmaf(wgt, v[j][0].w, a0.w);
            a1.x = fmaf(wgt, v[j][1].x, a1.x); a1.y = fmaf(wgt, v[j][1].y, a1.y);
            a1.z = fmaf(wgt, v[j][1].z, a1.z); a1.w = fmaf(wgt, v[j][1].w, a1.w);
        }
    }
    float* op = partial + ((size_t)sc * BS + b) * D2 + t * 8;
    reinterpret_cast<float4*>(op)[0] = a0;
    reinterpret_cast<float4*>(op)[1] = a1;
}

// ---------------------------------------------------------------------------
// k_norm: per b — global softmax stats from scoresT/maskT (coalesced),
// writes alignT and per-slice rescale r[b][sc] = exp(m_sc - m_g) * scale.
// Thread t owns s = 4t..4t+3 (so slice sc <-> threads 16sc..16sc+15).
// ---------------------------------------------------------------------------
__global__ __launch_bounds__(256) void k_norm(
    const float* __restrict__ scoresT, const float* __restrict__ maskT,
    float* __restrict__ alignT, float* __restrict__ rfac) {
    const int b = blockIdx.x, t = threadIdx.x, wave = t >> 6, lane = t & 63;
    __shared__ float redm[4], reds[4], redms[4];

    float4 sv = *reinterpret_cast<const float4*>(scoresT + (size_t)b * SL + t * 4);
    float4 mv = *reinterpret_cast<const float4*>(maskT + (size_t)b * SL + t * 4);

    float msl = fmaxf(fmaxf(sv.x, sv.y), fmaxf(sv.z, sv.w));
    msl = fmaxf(msl, __shfl_xor(msl, 1, 64));
    msl = fmaxf(msl, __shfl_xor(msl, 2, 64));
    msl = fmaxf(msl, __shfl_xor(msl, 4, 64));
    msl = fmaxf(msl, __shfl_xor(msl, 8, 64));     // slice max (16-lane group)
    float mg = msl;
    mg = fmaxf(mg, __shfl_xor(mg, 16, 64));
    mg = fmaxf(mg, __shfl_xor(mg, 32, 64));
    if (lane == 0) redm[wave] = mg;
    __syncthreads();
    mg = fmaxf(fmaxf(redm[0], redm[1]), fmaxf(redm[2], redm[3]));

    float e0 = __expf(sv.x - mg), e1 = __expf(sv.y - mg);
    float e2 = __expf(sv.z - mg), e3 = __expf(sv.w - mg);
    float sum  = e0 + e1 + e2 + e3;
    float msum = e0 * mv.x + e1 * mv.y + e2 * mv.z + e3 * mv.w;
    sum  = waveReduceAdd(sum);
    msum = waveReduceAdd(msum);
    if (lane == 0) { reds[wave] = sum; redms[wave] = msum; }
    __syncthreads();
    sum  = reds[0] + reds[1] + reds[2] + reds[3];
    msum = redms[0] + redms[1] + redms[2] + redms[3];

    const float inv   = 1.0f / sum;
    const float denom = msum * inv + 1e-8f;
    const float scale = inv / denom;

    float4 ao = make_float4(e0 * mv.x * scale, e1 * mv.y * scale,
                            e2 * mv.z * scale, e3 * mv.w * scale);
    *reinterpret_cast<float4*>(alignT + (size_t)b * SL + t * 4) = ao;

    if ((t & 15) == 0) rfac[b * NSC + (t >> 4)] = __expf(msl - mg) * scale;
}

// ---------------------------------------------------------------------------
// k_ctx: ctx[b][d] = sum_sc partial[sc][b][d] * r[b][sc].  grid (BS, 2).
// Fully coalesced reads and writes.
// ---------------------------------------------------------------------------
__global__ __launch_bounds__(256) void k_ctx(
    const float* __restrict__ partial, const float* __restrict__ rfac,
    float* __restrict__ ctx) {
    __shared__ float r[NSC];
    const int b = blockIdx.x, dc = blockIdx.y, t = threadIdx.x;
    if (t < NSC) r[t] = rfac[b * NSC + t];
    __syncthreads();
    const int d = dc * 1024 + t * 4;
    const float* pb = partial + (size_t)b * D2 + d;
    float4 acc = make_float4(0.f, 0.f, 0.f, 0.f);
#pragma unroll
    for (int sc = 0; sc < NSC; ++sc) {
        float4 p = *reinterpret_cast<const float4*>(pb + (size_t)sc * BS * D2);
        const float rv = r[sc];
        acc.x = fmaf(rv, p.x, acc.x); acc.y = fmaf(rv, p.y, acc.y);
        acc.z = fmaf(rv, p.z, acc.z); acc.w = fmaf(rv, p.w, acc.w);
    }
    *reinterpret_cast<float4*>(ctx + (size_t)b * D2 + d) = acc;
}

// ---------------------------------------------------------------------------
// k_gemm: split-K GEMM.  grid (CELL/16, KS5), block 256 = 4 waves.
// Stages the activation panel (ctx||ht) [64 b][192 j] into LDS (stride 193,
// conflict-free), then wave = 4 c-rows, lane = b; W via 8-deep nt loads.
// ---------------------------------------------------------------------------
#define FMA8(acc, r)                                                   \
    acc = fmaf(a[0], wa[r][0].x, acc); acc = fmaf(a[1], wa[r][0].y, acc); \
    acc = fmaf(a[2], wa[r][0].z, acc); acc = fmaf(a[3], wa[r][0].w, acc); \
    acc = fmaf(a[4], wa[r][1].x, acc); acc = fmaf(a[5], wa[r][1].y, acc); \
    acc = fmaf(a[6], wa[r][1].z, acc); acc = fmaf(a[7], wa[r][1].w, acc);

__global__ __launch_bounds__(256) void k_gemm(
    const float* __restrict__ ctx, const float* __restrict__ ht,
    const float* __restrict__ W, float* __restrict__ part5) {
    __shared__ float act[BS * 193];
    const int t = threadIdx.x, wave = t >> 6, lane = t & 63;
    const int jb = blockIdx.y * JS5;
    // stage activation panel
    for (int idx = t; idx < BS * (JS5 / 4); idx += 256) {
        const int row = idx / (JS5 / 4), c4 = idx % (JS5 / 4);
        const int jg = jb + c4 * 4;
        const float* src = (jg < D2) ? (ctx + (size_t)row * D2 + jg)
                                     : (ht + (size_t)row * HID + (jg - D2));
        float4 v = *reinterpret_cast<const float4*>(src);
        float* dst = act + row * 193 + c4 * 4;
        dst[0] = v.x; dst[1] = v.y; dst[2] = v.z; dst[3] = v.w;
    }
    __syncthreads();

    int c0 = blockIdx.x * 16 + wave * 4;
    c0 = __builtin_amdgcn_readfirstlane(c0);
    const float* w0 = W + (size_t)c0 * KCAT + jb;
    float acc0 = 0.f, acc1 = 0.f, acc2 = 0.f, acc3 = 0.f;
    for (int j = 0; j < JS5; j += 8) {
        float4 wa[4][2];
#pragma unroll
        for (int rr = 0; rr < 4; ++rr) {
            wa[rr][0] = ntload(w0 + rr * KCAT + j);
            wa[rr][1] = ntload(w0 + rr * KCAT + j + 4);
        }
        float a[8];
#pragma unroll
        for (int k = 0; k < 8; ++k) a[k] = act[lane * 193 + j + k];
        FMA8(acc0, 0) FMA8(acc1, 1) FMA8(acc2, 2) FMA8(acc3, 3)
    }
    float* p = part5 + ((size_t)blockIdx.y * CELL + c0) * BS + lane;
    p[0 * BS] = acc0; p[1 * BS] = acc1; p[2 * BS] = acc2; p[3 * BS] = acc3;
}

// ---------------------------------------------------------------------------
// k_finish: out[b][c] = tanh(bias[c] + sum_ks part5[ks][c][b]).
// grid 64 blocks, 16 c each; coalesced part5 reads; LDS transpose so the
// out writes are 64B-segment coalesced.
// ---------------------------------------------------------------------------
__global__ __launch_bounds__(256) void k_finish(
    const float* __restrict__ part5, const float* __restrict__ bias,
    float* __restrict__ out) {
    __shared__ float tile[16][65];
    const int ct = blockIdx.x;
    const int t = threadIdx.x, b = t & 63, cl = t >> 6;   // cl 0..3
    float acc[4] = {0.f, 0.f, 0.f, 0.f};
#pragma unroll
    for (int ks = 0; ks < KS5; ++ks) {
#pragma unroll
        for (int i = 0; i < 4; ++i) {
            const int c = ct * 16 + cl * 4 + i;
            acc[i] += part5[((size_t)ks * CELL + c) * BS + b];
        }
    }
#pragma unroll
    for (int i = 0; i < 4; ++i) {
        const int c_local = cl * 4 + i;
        tile[c_local][b] = tanhf(acc[i] + bias[ct * 16 + c_local]);
    }
    __syncthreads();
    const int c_w = t & 15, bq = t >> 4;                  // bq 0..15
#pragma unroll
    for (int i = 0; i < 4; ++i) {
        const int b_w = bq + 16 * i;
        out[(size_t)b_w * CELL + ct * 16 + c_w] = tile[c_w][b_w];
    }
}

// ---------------------------------------------------------------------------
extern "C" void kernel_launch(void* const* d_in, const int* in_sizes, int n_in,
                              void* d_out, int out_size, void* d_ws, size_t ws_size,
                              hipStream_t stream) {
    const float* Wh   = (const float*)d_in[0];   // (SL, BS, HID)
    const float* ht   = (const float*)d_in[1];   // (BS, HID)
    const float* mask = (const float*)d_in[2];   // (SL, BS)
    const float* hs   = (const float*)d_in[3];   // (SL, BS, D2)
    const float* W    = (const float*)d_in[4];   // (CELL, KCAT)
    const float* bias = (const float*)d_in[5];   // (CELL,)

    float* out    = (float*)d_out;
    float* htilde = out;                       // (BS, CELL)
    float* alignT = out + (size_t)BS * CELL;   // (BS, SL)

    // workspace (floats):
    // scoresT | maskT | partial(NSC*BS*D2) | rfac(BS*NSC) | ctx(BS*D2) | part5
    float* ws      = (float*)d_ws;
    float* scoresT = ws;
    float* maskT   = scoresT + (size_t)BS * SL;
    float* partial = maskT + (size_t)BS * SL;
    float* rfac    = partial + (size_t)NSC * BS * D2;
    float* ctx     = rfac + (size_t)BS * NSC;
    float* part5   = ctx + (size_t)BS * D2;

    dim3 gf(BS, NSC);
    k_fused<<<gf, 256, 0, stream>>>(Wh, ht, mask, hs, scoresT, maskT, partial);
    k_norm<<<BS, 256, 0, stream>>>(scoresT, maskT, alignT, rfac);
    dim3 gc(BS, 2);
    k_ctx<<<gc, 256, 0, stream>>>(partial, rfac, ctx);
    dim3 g5(CELL / 16, KS5);
    k_gemm<<<g5, 256, 0, stream>>>(ctx, ht, W, part5);
    k_finish<<<BS, 256, 0, stream>>>(part5, bias, htilde);
}

// Round 6
// 186.720 us; speedup vs baseline: 1.0209x; 1.0209x over previous
//
#include <hip/hip_runtime.h>
#include <math.h>

#define SL   1024
#define BS   64
#define HID  1024
#define D2   2048            // 2*CELL
#define KCAT 3072            // 2*CELL + HID
#define CELL 1024
#define NSC  16              // s-slices for the fused attention kernel
#define SPB  (SL / NSC)      // 64 s per block
#define KS5  16              // K-split for the output GEMM
#define JS5  (KCAT / KS5)    // 192 j per slice

typedef float vfloat4 __attribute__((ext_vector_type(4)));

__device__ __forceinline__ float4 ntload(const float* p) {
    vfloat4 v = __builtin_nontemporal_load(reinterpret_cast<const vfloat4*>(p));
    return make_float4(v.x, v.y, v.z, v.w);
}

__device__ __forceinline__ float waveReduceAdd(float v) {
#pragma unroll
    for (int o = 32; o >= 1; o >>= 1) v += __shfl_xor(v, o, 64);
    return v;
}
__device__ __forceinline__ float waveReduceMax(float v) {
#pragma unroll
    for (int o = 32; o >= 1; o >>= 1) v = fmaxf(v, __shfl_xor(v, o, 64));
    return v;
}

// ---------------------------------------------------------------------------
// k_fused (v2): per (b, s-slice) block, 256 threads = 4 waves.
// Pass 1: each WAVE owns 16 of the 64 s-rows (HID = 64 lanes x 4 float4, so
//         a single wave computes a full dot with shuffle-reduce only — no
//         block barrier per score, 2 barriers total in the kernel).
// Pass 2: slice-partial context with weights exp(score - m_slice) * mask.
// Also writes scoresT[b][s], maskT[b][s] for the (coalesced) normalizer.
// ---------------------------------------------------------------------------
__global__ __launch_bounds__(256) void k_fused(
    const float* __restrict__ Wh, const float* __restrict__ ht,
    const float* __restrict__ mask, const float* __restrict__ hs,
    float* __restrict__ scoresT, float* __restrict__ maskT,
    float* __restrict__ partial) {
    __shared__ float sco[SPB];
    __shared__ float wgt[SPB];
    const int b = blockIdx.x, sc = blockIdx.y, s0 = sc * SPB;
    const int t = threadIdx.x, wave = t >> 6, lane = t & 63;

    // h_t fragment for this lane (replicated per wave)
    const float* htb = ht + (size_t)b * HID;
    float4 hreg[4];
#pragma unroll
    for (int k = 0; k < 4; ++k)
        hreg[k] = *reinterpret_cast<const float4*>(htb + lane * 4 + k * 256);

    float mv = 0.f;
    if (t < SPB) mv = mask[(size_t)(s0 + t) * BS + b];

    // ---- pass 1: 16 scores per wave, 2 at a time (8 float4 in flight) ----
    const size_t wstride = (size_t)BS * HID;
    const float* wb = Wh + ((size_t)(s0 + wave * 16) * BS + b) * HID + lane * 4;
    for (int i = 0; i < 16; i += 2) {
        float4 w0[4], w1[4];
#pragma unroll
        for (int k = 0; k < 4; ++k) {
            w0[k] = ntload(wb + (size_t)(i + 0) * wstride + k * 256);
            w1[k] = ntload(wb + (size_t)(i + 1) * wstride + k * 256);
        }
        float d0 = 0.f, d1 = 0.f;
#pragma unroll
        for (int k = 0; k < 4; ++k) {
            d0 = fmaf(w0[k].x, hreg[k].x, fmaf(w0[k].y, hreg[k].y,
                 fmaf(w0[k].z, hreg[k].z, fmaf(w0[k].w, hreg[k].w, d0))));
            d1 = fmaf(w1[k].x, hreg[k].x, fmaf(w1[k].y, hreg[k].y,
                 fmaf(w1[k].z, hreg[k].z, fmaf(w1[k].w, hreg[k].w, d1))));
        }
        d0 = waveReduceAdd(d0);
        d1 = waveReduceAdd(d1);
        if (lane == 0) {
            sco[wave * 16 + i]     = d0;
            sco[wave * 16 + i + 1] = d1;
        }
    }
    __syncthreads();

    // slice max: every wave redundantly reduces sco[0..63] (no extra barrier)
    const float sv = sco[lane];
    const float m = waveReduceMax(sv);

    if (t < SPB) {                        // wave 0 only; sv == sco[t]
        scoresT[(size_t)b * SL + s0 + t] = sv;
        maskT[(size_t)b * SL + s0 + t]   = mv;
        wgt[t] = __expf(sv - m) * mv;     // slice-local weights, <= 1
    }
    __syncthreads();

    // ---- pass 2: weighted context over the slice (16 float4 in flight) ----
    const float* hbase = hs + ((size_t)s0 * BS + b) * D2 + t * 8;
    const size_t hstride = (size_t)BS * D2;
    float4 a0 = make_float4(0.f, 0.f, 0.f, 0.f);
    float4 a1 = make_float4(0.f, 0.f, 0.f, 0.f);
    for (int s = 0; s < SPB; s += 8) {
        float4 v[8][2];
#pragma unroll
        for (int j = 0; j < 8; ++j) {
            const float* p = hbase + (size_t)(s + j) * hstride;
            v[j][0] = ntload(p);
            v[j][1] = ntload(p + 4);
        }
#pragma unroll
        for (int j = 0; j < 8; ++j) {
            const float w = wgt[s + j];
            a0.x = fmaf(w, v[j][0].x, a0.x); a0.y = fmaf(w, v[j][0].y, a0.y);
            a0.z = fmaf(w, v[j][0].z, a0.z); a0.w = fmaf(w, v[j][0].w, a0.w);
            a1.x = fmaf(w, v[j][1].x, a1.x); a1.y = fmaf(w, v[j][1].y, a1.y);
            a1.z = fmaf(w, v[j][1].z, a1.z); a1.w = fmaf(w, v[j][1].w, a1.w);
        }
    }
    float* op = partial + ((size_t)sc * BS + b) * D2 + t * 8;
    reinterpret_cast<float4*>(op)[0] = a0;
    reinterpret_cast<float4*>(op)[1] = a1;
}

// ---------------------------------------------------------------------------
// k_norm: per b — global softmax stats from scoresT/maskT (coalesced),
// writes alignT and per-slice rescale r[b][sc] = exp(m_sc - m_g) * scale.
// Thread t owns s = 4t..4t+3 (slice sc <-> threads 16sc..16sc+15).
// ---------------------------------------------------------------------------
__global__ __launch_bounds__(256) void k_norm(
    const float* __restrict__ scoresT, const float* __restrict__ maskT,
    float* __restrict__ alignT, float* __restrict__ rfac) {
    const int b = blockIdx.x, t = threadIdx.x, wave = t >> 6, lane = t & 63;
    __shared__ float redm[4], reds[4], redms[4];

    float4 sv = *reinterpret_cast<const float4*>(scoresT + (size_t)b * SL + t * 4);
    float4 mv = *reinterpret_cast<const float4*>(maskT + (size_t)b * SL + t * 4);

    float msl = fmaxf(fmaxf(sv.x, sv.y), fmaxf(sv.z, sv.w));
    msl = fmaxf(msl, __shfl_xor(msl, 1, 64));
    msl = fmaxf(msl, __shfl_xor(msl, 2, 64));
    msl = fmaxf(msl, __shfl_xor(msl, 4, 64));
    msl = fmaxf(msl, __shfl_xor(msl, 8, 64));     // slice max (16-lane group)
    float mg = msl;
    mg = fmaxf(mg, __shfl_xor(mg, 16, 64));
    mg = fmaxf(mg, __shfl_xor(mg, 32, 64));
    if (lane == 0) redm[wave] = mg;
    __syncthreads();
    mg = fmaxf(fmaxf(redm[0], redm[1]), fmaxf(redm[2], redm[3]));

    float e0 = __expf(sv.x - mg), e1 = __expf(sv.y - mg);
    float e2 = __expf(sv.z - mg), e3 = __expf(sv.w - mg);
    float sum  = e0 + e1 + e2 + e3;
    float msum = e0 * mv.x + e1 * mv.y + e2 * mv.z + e3 * mv.w;
    sum  = waveReduceAdd(sum);
    msum = waveReduceAdd(msum);
    if (lane == 0) { reds[wave] = sum; redms[wave] = msum; }
    __syncthreads();
    sum  = reds[0] + reds[1] + reds[2] + reds[3];
    msum = redms[0] + redms[1] + redms[2] + redms[3];

    const float inv   = 1.0f / sum;
    const float denom = msum * inv + 1e-8f;
    const float scale = inv / denom;

    float4 ao = make_float4(e0 * mv.x * scale, e1 * mv.y * scale,
                            e2 * mv.z * scale, e3 * mv.w * scale);
    *reinterpret_cast<float4*>(alignT + (size_t)b * SL + t * 4) = ao;

    if ((t & 15) == 0) rfac[b * NSC + (t >> 4)] = __expf(msl - mg) * scale;
}

// ---------------------------------------------------------------------------
// k_ctx: ctx[b][d] = sum_sc partial[sc][b][d] * r[b][sc].  grid (BS, 2).
// ---------------------------------------------------------------------------
__global__ __launch_bounds__(256) void k_ctx(
    const float* __restrict__ partial, const float* __restrict__ rfac,
    float* __restrict__ ctx) {
    __shared__ float r[NSC];
    const int b = blockIdx.x, dc = blockIdx.y, t = threadIdx.x;
    if (t < NSC) r[t] = rfac[b * NSC + t];
    __syncthreads();
    const int d = dc * 1024 + t * 4;
    const float* pb = partial + (size_t)b * D2 + d;
    float4 acc = make_float4(0.f, 0.f, 0.f, 0.f);
#pragma unroll
    for (int sc = 0; sc < NSC; ++sc) {
        float4 p = *reinterpret_cast<const float4*>(pb + (size_t)sc * BS * D2);
        const float rv = r[sc];
        acc.x = fmaf(rv, p.x, acc.x); acc.y = fmaf(rv, p.y, acc.y);
        acc.z = fmaf(rv, p.z, acc.z); acc.w = fmaf(rv, p.w, acc.w);
    }
    *reinterpret_cast<float4*>(ctx + (size_t)b * D2 + d) = acc;
}

// ---------------------------------------------------------------------------
// k_gemm: split-K GEMM.  grid (CELL/16, KS5), block 256 = 4 waves.
// Stages the activation panel (ctx||ht) [64 b][192 j] into LDS (stride 193,
// conflict-free), then wave = 4 c-rows, lane = b; W via 8-deep nt loads.
// ---------------------------------------------------------------------------
#define FMA8(acc, r)                                                   \
    acc = fmaf(a[0], wa[r][0].x, acc); acc = fmaf(a[1], wa[r][0].y, acc); \
    acc = fmaf(a[2], wa[r][0].z, acc); acc = fmaf(a[3], wa[r][0].w, acc); \
    acc = fmaf(a[4], wa[r][1].x, acc); acc = fmaf(a[5], wa[r][1].y, acc); \
    acc = fmaf(a[6], wa[r][1].z, acc); acc = fmaf(a[7], wa[r][1].w, acc);

__global__ __launch_bounds__(256) void k_gemm(
    const float* __restrict__ ctx, const float* __restrict__ ht,
    const float* __restrict__ W, float* __restrict__ part5) {
    __shared__ float act[BS * 193];
    const int t = threadIdx.x, wave = t >> 6, lane = t & 63;
    const int jb = blockIdx.y * JS5;
    for (int idx = t; idx < BS * (JS5 / 4); idx += 256) {
        const int row = idx / (JS5 / 4), c4 = idx % (JS5 / 4);
        const int jg = jb + c4 * 4;
        const float* src = (jg < D2) ? (ctx + (size_t)row * D2 + jg)
                                     : (ht + (size_t)row * HID + (jg - D2));
        float4 v = *reinterpret_cast<const float4*>(src);
        float* dst = act + row * 193 + c4 * 4;
        dst[0] = v.x; dst[1] = v.y; dst[2] = v.z; dst[3] = v.w;
    }
    __syncthreads();

    int c0 = blockIdx.x * 16 + wave * 4;
    c0 = __builtin_amdgcn_readfirstlane(c0);
    const float* w0 = W + (size_t)c0 * KCAT + jb;
    float acc0 = 0.f, acc1 = 0.f, acc2 = 0.f, acc3 = 0.f;
    for (int j = 0; j < JS5; j += 8) {
        float4 wa[4][2];
#pragma unroll
        for (int rr = 0; rr < 4; ++rr) {
            wa[rr][0] = ntload(w0 + rr * KCAT + j);
            wa[rr][1] = ntload(w0 + rr * KCAT + j + 4);
        }
        float a[8];
#pragma unroll
        for (int k = 0; k < 8; ++k) a[k] = act[lane * 193 + j + k];
        FMA8(acc0, 0) FMA8(acc1, 1) FMA8(acc2, 2) FMA8(acc3, 3)
    }
    float* p = part5 + ((size_t)blockIdx.y * CELL + c0) * BS + lane;
    p[0 * BS] = acc0; p[1 * BS] = acc1; p[2 * BS] = acc2; p[3 * BS] = acc3;
}

// ---------------------------------------------------------------------------
// k_finish: out[b][c] = tanh(bias[c] + sum_ks part5[ks][c][b]).
// ---------------------------------------------------------------------------
__global__ __launch_bounds__(256) void k_finish(
    const float* __restrict__ part5, const float* __restrict__ bias,
    float* __restrict__ out) {
    __shared__ float tile[16][65];
    const int ct = blockIdx.x;
    const int t = threadIdx.x, b = t & 63, cl = t >> 6;   // cl 0..3
    float acc[4] = {0.f, 0.f, 0.f, 0.f};
#pragma unroll
    for (int ks = 0; ks < KS5; ++ks) {
#pragma unroll
        for (int i = 0; i < 4; ++i) {
            const int c = ct * 16 + cl * 4 + i;
            acc[i] += part5[((size_t)ks * CELL + c) * BS + b];
        }
    }
#pragma unroll
    for (int i = 0; i < 4; ++i) {
        const int c_local = cl * 4 + i;
        tile[c_local][b] = tanhf(acc[i] + bias[ct * 16 + c_local]);
    }
    __syncthreads();
    const int c_w = t & 15, bq = t >> 4;                  // bq 0..15
#pragma unroll
    for (int i = 0; i < 4; ++i) {
        const int b_w = bq + 16 * i;
        out[(size_t)b_w * CELL + ct * 16 + c_w] = tile[c_w][b_w];
    }
}

// ---------------------------------------------------------------------------
extern "C" void kernel_launch(void* const* d_in, const int* in_sizes, int n_in,
                              void* d_out, int out_size, void* d_ws, size_t ws_size,
                              hipStream_t stream) {
    const float* Wh   = (const float*)d_in[0];   // (SL, BS, HID)
    const float* ht   = (const float*)d_in[1];   // (BS, HID)
    const float* mask = (const float*)d_in[2];   // (SL, BS)
    const float* hs   = (const float*)d_in[3];   // (SL, BS, D2)
    const float* W    = (const float*)d_in[4];   // (CELL, KCAT)
    const float* bias = (const float*)d_in[5];   // (CELL,)

    float* out    = (float*)d_out;
    float* htilde = out;                       // (BS, CELL)
    float* alignT = out + (size_t)BS * CELL;   // (BS, SL)

    // workspace (floats):
    // scoresT | maskT | partial(NSC*BS*D2) | rfac(BS*NSC) | ctx(BS*D2) | part5
    float* ws      = (float*)d_ws;
    float* scoresT = ws;
    float* maskT   = scoresT + (size_t)BS * SL;
    float* partial = maskT + (size_t)BS * SL;
    float* rfac    = partial + (size_t)NSC * BS * D2;
    float* ctx     = rfac + (size_t)BS * NSC;
    float* part5   = ctx + (size_t)BS * D2;

    dim3 gf(BS, NSC);
    k_fused<<<gf, 256, 0, stream>>>(Wh, ht, mask, hs, scoresT, maskT, partial);
    k_norm<<<BS, 256, 0, stream>>>(scoresT, maskT, alignT, rfac);
    dim3 gc(BS, 2);
    k_ctx<<<gc, 256, 0, stream>>>(partial, rfac, ctx);
    dim3 g5(CELL / 16, KS5);
    k_gemm<<<g5, 256, 0, stream>>>(ctx, ht, W, part5);
    k_finish<<<BS, 256, 0, stream>>>(part5, bias, htilde);
}